// Round 4
// baseline (182.870 us; speedup 1.0000x reference)
//
#include <hip/hip_runtime.h>
#include <hip/hip_bf16.h>
#include <stdint.h>

// B,C,H,W = 2,64,96,96. Inputs fp32, output fp32.
// proj4: QKV 1x1 convs. x tile (64c x 64px, 16KB) staged to LDS via
//        global_load_lds 16B (4 instr/thread, coalesced) -- replaces 64
//        scalar 4B global loads/thread of proj3 (suspected ~dozens of µs,
//        invisible under rocprof top-5 cutoff). Compute: wave-uniform
//        weight rows (scalar loads) x conflict-free ds_read_b32.
// attn11: LDS-staged flash attention (attn10 structure) with lsum moved
//        BACK to the ones-row MFMA (round-3 put it on the VALU: VALUBusy
//        39% > MfmaUtil 25% -- wrong pipe), plus s_setprio around MFMA
//        clusters (T5).
// combine: sum G key-split partials, normalize, + gamma*attn + x.
#define BB 2
#define CC 64
#define PP 9216
#define QTILES 144               // PP/64
#define LOG2E 1.4426950408889634f
// big-constant Schraudolph: low16(E*128 + 16248.665 + 1.5*2^23) = bf16 bits of 2^E
#define SCH_BC 12599160.0f

typedef unsigned short ushort;
typedef __attribute__((ext_vector_type(8))) short short8;
typedef __attribute__((ext_vector_type(4))) float floatx4;
typedef __attribute__((ext_vector_type(4))) int intx4;

__device__ __forceinline__ ushort f2bf(float f) {
    unsigned int u = __float_as_uint(f);
    u = (u + 0x7fffu + ((u >> 16) & 1u)) >> 16;   // RNE
    return (ushort)u;
}

// 2^e0, 2^e1 as packed bf16 pair: add-big-constant Schraudolph (no v_cvt),
// then one v_perm_b32 splices the two low16 halves.
__device__ __forceinline__ unsigned int exp2_pk_bf16(float e0, float e1) {
    const float t0 = fmaf(e0, 128.f, SCH_BC);
    const float t1 = fmaf(e1, 128.f, SCH_BC);
    // result bytes: [t0.b0, t0.b1, t1.b0, t1.b1]
    return __builtin_amdgcn_perm(__float_as_uint(t1), __float_as_uint(t0),
                                 0x05040100u);
}

__device__ __forceinline__ void gload16_lds(const void* g, void* lds_base) {
    __builtin_amdgcn_global_load_lds(
        (const __attribute__((address_space(1))) unsigned int*)g,
        (__attribute__((address_space(3))) unsigned int*)lds_base, 16, 0, 0);
}

// ---------------------------------------------------------------------------
// Kernel 1: QKV projection, LDS-staged. 576 blocks x 256 (4 waves; 2 blocks
// per 64-px tile, each covering 40 of the 80 output rows; wave = 64 px x 10
// rows). Stage: x tile [c 0..63][px 0..63] f32 -> 16KB LDS, 4x
// global_load_lds(16B) per thread, linear slot = i*256+tid (dest =
// wave-uniform base + lane*16). Rows 0-7: q (*LOG2E), 8-15: k, 16-79: v.
// V keys permuted within 32-groups: slot = ((k>>2)&3)*8 + ((k>>4)&1)*4 + (k&3)
// so PV's B-operand slot k'=quad*8+j matches QK's D[key][q] output rows.
// ---------------------------------------------------------------------------
__global__ __launch_bounds__(256)
void proj4(const float* __restrict__ x,
           const float* __restrict__ Wq, const float* __restrict__ bq,
           const float* __restrict__ Wk, const float* __restrict__ bk,
           const float* __restrict__ Wv, const float* __restrict__ bv,
           ushort* __restrict__ qbuf, ushort* __restrict__ kbuf,
           ushort* __restrict__ vfw)
{
    __shared__ __align__(16) float xs[64 * 64];   // [c][px], 16 KB

    const int tid  = threadIdx.x;
    const int lane = tid & 63;
    const int w    = tid >> 6;                    // wave id 0..3 (uniform)
    const int blk = blockIdx.x;
    const int b     = blk / (2 * QTILES);
    const int rem   = blk % (2 * QTILES);
    const int ptile = rem >> 1;
    const int rhalf = rem & 1;
    const int p0    = ptile * 64;
    const int p     = p0 + lane;
    const int r0    = rhalf * 40 + w * 10;        // this wave's 10 rows

    // ---- stage x tile: 1024 float4 slots; slot s = i*256 + tid ----
    const int w64 = tid & ~63;                    // w*64 (wave-uniform)
#pragma unroll
    for (int i = 0; i < 4; ++i) {
        const int s  = i * 256 + tid;
        const int c  = s >> 4;
        const int j4 = (s & 15) << 2;
        gload16_lds(x + ((size_t)(b * 64 + c)) * PP + p0 + j4,
                    (char*)xs + ((size_t)(i * 256 + w64)) * 16);
    }
    __syncthreads();   // vmcnt(0) drain: xs ready

    const float* wrow[10];
#pragma unroll
    for (int r = 0; r < 10; ++r) {
        const int row = r0 + r;
        wrow[r] = (row < 8) ? (Wq + row * 64)
                : (row < 16) ? (Wk + (row - 8) * 64)
                : (Wv + (row - 16) * 64);
    }

    float acc[10];
#pragma unroll
    for (int r = 0; r < 10; ++r) acc[r] = 0.f;
#pragma unroll
    for (int c = 0; c < 64; ++c) {
        const float xc = xs[c * 64 + lane];       // conflict-free (2-way)
#pragma unroll
        for (int r = 0; r < 10; ++r)
            acc[r] = fmaf(wrow[r][c], xc, acc[r]);   // weights via scalar loads
    }

#pragma unroll
    for (int r = 0; r < 10; ++r) {
        const int row = r0 + r;
        if (row < 8) {
            const float v = (acc[r] + bq[row]) * LOG2E;
            qbuf[((size_t)b * PP + p) * 8 + row] = f2bf(v);
        } else if (row < 16) {
            const float v = acc[r] + bk[row - 8];
            kbuf[((size_t)b * PP + p) * 8 + (row - 8)] = f2bf(v);
        } else {
            const int co = row - 16;
            const float v = acc[r] + bv[co];
            const int pl = p & 31;     // slot permutation within 32-group
            const int ps = (p & ~31) | ((((pl >> 2) & 3) << 3) | (((pl >> 4) & 1) << 2) | (pl & 3));
            vfw[((size_t)b * 64 + co) * PP + ps] = f2bf(v);
        }
    }
}

// ---------------------------------------------------------------------------
// Kernel 2: LDS-staged MFMA flash attention. Grid = G*BB*QTILES blocks of 128
// (2 waves = the two 32-key halves of each 64-key tile; both share one staged
// K+V tile: K 1KB + V 8KB per buffer, double-buffered, 18.25KB LDS total,
// epilogue smerge overlays the dead stage buffers).
// Stage: wave0 = K(1 instr) + V ch-rows 0-31 (4 instrs); wave1 = rows 32-63.
// V LDS layout: [ch row 0..63][8 chunks of 16B], chunk_pos = logical ^ (row&7)
// (swizzle applied on global source; ds_read applies the same XOR).
// QK: E = mfma(A=K, B=Q) -> D[key][q]; Q k-slots >=8 zero, K quads broadcast.
// P packed in regs as PV B-operand (V key-permuted). lsum via ones-row MFMA
// over the same bf16 P (matrix pipe has headroom; VALU does not). s_setprio
// wraps the MFMA clusters (T5).
// ---------------------------------------------------------------------------
__global__ __launch_bounds__(128, 3)
void attn11(const ushort* __restrict__ qbuf, const ushort* __restrict__ kbuf,
            const ushort* __restrict__ vfw,
            ushort* __restrict__ accp, float* __restrict__ lsump,
            int keysPerG, int numTiles)
{
    // 0..9216: buf0 (V 8KB + K 1KB) | 9216..18432: buf1 | 18432..18688: slsum
    // smerge (16KB f32) overlays 0..16384 after the loop.
    __shared__ __align__(16) char sbuf[18688];
    float* smerge = (float*)sbuf;
    float* slsum  = (float*)(sbuf + 18432);

    const int tid  = threadIdx.x;
    const int lane = tid & 63;
    const int kh   = tid >> 6;        // wave id = key half (0/1)
    const int col  = lane & 15;
    const int quad = lane >> 4;

    const int qt = blockIdx.x % QTILES;
    const int gb = blockIdx.x / QTILES;
    const int b  = gb % BB;
    const int g  = gb / BB;
    const int q0 = qt * 64;

    const short8 zf = {0, 0, 0, 0, 0, 0, 0, 0};
    const short vone = (short)0x3F80;                 // bf16 1.0
    const short8 vones = {vone, vone, vone, vone, vone, vone, vone, vone};

    // Q fragments (B-operand: B[k=d=quad*8+j][n=q=col]); only quad 0 real.
    short8 qfragB[4];
#pragma unroll
    for (int qh = 0; qh < 4; ++qh)
        qfragB[qh] = (quad == 0)
            ? *(const short8*)(qbuf + ((size_t)b * PP + q0 + qh * 16 + col) * 8)
            : zf;

    floatx4 acc[4][4];
#pragma unroll
    for (int qh = 0; qh < 4; ++qh)
#pragma unroll
        for (int cb = 0; cb < 4; ++cb) acc[qh][cb] = (floatx4){0.f, 0.f, 0.f, 0.f};
    floatx4 accLh[4];
#pragma unroll
    for (int qh = 0; qh < 4; ++qh) accLh[qh] = (floatx4){0.f, 0.f, 0.f, 0.f};

    const ushort* kB = kbuf + (size_t)b * PP * 8;
    const ushort* vB = vfw + (size_t)b * 64 * PP;
    const int kwbase = g * keysPerG;

    // per-lane staging geometry: lane covers (row-in-8-group vr, chunk_pos lane&7)
    const int vr = lane >> 3;                 // 0..7
    const int vc = (lane & 7) ^ vr;           // swizzled logical chunk for this slot

    auto stage = [&](int t) {
        const int kw = kwbase + t * 64;
        char* Vb = sbuf + (t & 1) * 9216;
        if (kh == 0)
            gload16_lds(kB + (size_t)(kw + lane) * 8, Vb + 8192);  // K: 64 rows x 16B
        const int j0 = kh * 4;
#pragma unroll
        for (int j = 0; j < 4; ++j) {
            const int r = (j0 + j) * 8 + vr;                       // ch row 0..63
            gload16_lds(vB + (size_t)r * PP + kw + vc * 8, Vb + (j0 + j) * 1024);
        }
    };

    auto compute = [&](int t) {
        const char* Vb = sbuf + (t & 1) * 9216;
        const ushort* Kl = (const ushort*)(Vb + 8192);
        // K A-operand rows = keys; all quads read quad0's 16B (broadcast, slots
        // >=8 multiply Q zeros).
        const short8 kf0 = *(const short8*)(Kl + (kh * 32 + col) * 8);
        const short8 kf1 = *(const short8*)(Kl + (kh * 32 + 16 + col) * 8);
        short8 vf[4];
        const int ce = (kh * 4 + quad) ^ (col & 7);   // swizzled chunk to read
#pragma unroll
        for (int cb = 0; cb < 4; ++cb)
            vf[cb] = *(const short8*)(Vb + ((cb * 16 + col) * 8 + ce) * 16);

#pragma unroll
        for (int qh = 0; qh < 4; ++qh) {
            __builtin_amdgcn_s_setprio(1);
            const floatx4 E0 = __builtin_amdgcn_mfma_f32_16x16x32_bf16(
                kf0, qfragB[qh], (floatx4){0.f, 0.f, 0.f, 0.f}, 0, 0, 0);
            const floatx4 E1 = __builtin_amdgcn_mfma_f32_16x16x32_bf16(
                kf1, qfragB[qh], (floatx4){0.f, 0.f, 0.f, 0.f}, 0, 0, 0);
            __builtin_amdgcn_s_setprio(0);

            // Schraudolph bf16 P, packed pairs (slots quad*8 + 0..7)
            intx4 pi;
            pi.x = (int)exp2_pk_bf16(E0[0], E0[1]);
            pi.y = (int)exp2_pk_bf16(E0[2], E0[3]);
            pi.z = (int)exp2_pk_bf16(E1[0], E1[1]);
            pi.w = (int)exp2_pk_bf16(E1[2], E1[3]);
            const short8 pf = __builtin_bit_cast(short8, pi);

            __builtin_amdgcn_s_setprio(1);
            accLh[qh] = __builtin_amdgcn_mfma_f32_16x16x32_bf16(vones, pf, accLh[qh], 0, 0, 0);
#pragma unroll
            for (int cb = 0; cb < 4; ++cb)
                acc[qh][cb] = __builtin_amdgcn_mfma_f32_16x16x32_bf16(
                    vf[cb], pf, acc[qh][cb], 0, 0, 0);
            __builtin_amdgcn_s_setprio(0);
        }
    };

    // ---- 2-phase staged main loop ----
    stage(0);
    __syncthreads();                 // drains vmcnt(0): buf0 ready
    for (int t = 0; t < numTiles; ++t) {
        if (t + 1 < numTiles) stage(t + 1);   // into the other buffer
        compute(t);
        __syncthreads();             // stage(t+1) complete + buf[t] reads done
    }

    // ---- merge the two waves' key-halves via LDS; wave 0 stores ----
    if (kh == 1) {
#pragma unroll
        for (int qh = 0; qh < 4; ++qh)
#pragma unroll
            for (int cb = 0; cb < 4; ++cb)
#pragma unroll
                for (int r = 0; r < 4; ++r)
                    smerge[(cb * 16 + quad * 4 + r) * 64 + qh * 16 + col] = acc[qh][cb][r];
        if (quad == 0)
#pragma unroll
            for (int qh = 0; qh < 4; ++qh)
                slsum[qh * 16 + col] = accLh[qh][0];
    }
    __syncthreads();
    if (kh == 0) {
        ushort* ab = accp + ((size_t)g * BB + b) * CC * PP;
#pragma unroll
        for (int qh = 0; qh < 4; ++qh)
#pragma unroll
            for (int cb = 0; cb < 4; ++cb)
#pragma unroll
                for (int r = 0; r < 4; ++r) {
                    const int c = cb * 16 + quad * 4 + r;
                    const float v = acc[qh][cb][r] + smerge[c * 64 + qh * 16 + col];
                    ab[(size_t)c * PP + q0 + qh * 16 + col] = f2bf(v);
                }
        if (quad == 0) {
            float* lb = lsump + ((size_t)g * BB + b) * PP + q0;
#pragma unroll
            for (int qh = 0; qh < 4; ++qh)
                lb[qh * 16 + col] = accLh[qh][0] + slsum[qh * 16 + col];
        }
    }
}

// ---------------------------------------------------------------------------
// Kernel 3: combine G partials, normalize, + gamma*attn + x. 576 x 256,
// 8 consecutive pixels per thread (layouts already [b][c][p]-major).
// ---------------------------------------------------------------------------
__global__ __launch_bounds__(256)
void combine(const ushort* __restrict__ accp, const float* __restrict__ lsump,
             const float* __restrict__ x, const float* __restrict__ gamma,
             float* __restrict__ out, int G)
{
    const size_t i8 = ((size_t)blockIdx.x * 256 + threadIdx.x) * 8;
    const int b = (int)(i8 / ((size_t)CC * PP));
    const int p = (int)(i8 % PP);
    const float gm = gamma[0];

    float asum[8] = {}, lst[8] = {};
    for (int g = 0; g < G; ++g) {
        const uint4 av = *(const uint4*)(accp + (size_t)g * (BB * CC * PP) + i8);
        const unsigned int u[4] = {av.x, av.y, av.z, av.w};
#pragma unroll
        for (int k = 0; k < 4; ++k) {
            asum[2 * k]     += __uint_as_float(u[k] << 16);
            asum[2 * k + 1] += __uint_as_float(u[k] & 0xffff0000u);
        }
        const float* lp = lsump + ((size_t)g * BB + b) * PP + p;
        const float4 l0 = *(const float4*)lp;
        const float4 l1 = *(const float4*)(lp + 4);
        lst[0] += l0.x; lst[1] += l0.y; lst[2] += l0.z; lst[3] += l0.w;
        lst[4] += l1.x; lst[5] += l1.y; lst[6] += l1.z; lst[7] += l1.w;
    }

    const float4 x0 = *(const float4*)(x + i8);
    const float4 x1 = *(const float4*)(x + i8 + 4);
    float o[8] = {x0.x, x0.y, x0.z, x0.w, x1.x, x1.y, x1.z, x1.w};
#pragma unroll
    for (int j = 0; j < 8; ++j)
        o[j] = fmaf(asum[j], gm / fmaxf(lst[j], 1e-30f), o[j]);
    *(float4*)(out + i8)     = make_float4(o[0], o[1], o[2], o[3]);
    *(float4*)(out + i8 + 4) = make_float4(o[4], o[5], o[6], o[7]);
}

// ---------------------------------------------------------------------------
extern "C" void kernel_launch(void* const* d_in, const int* in_sizes, int n_in,
                              void* d_out, int out_size, void* d_ws, size_t ws_size,
                              hipStream_t stream)
{
    const float* x     = (const float*)d_in[0];
    const float* Wq    = (const float*)d_in[1];
    const float* bq    = (const float*)d_in[2];
    const float* Wk    = (const float*)d_in[3];
    const float* bk    = (const float*)d_in[4];
    const float* Wv    = (const float*)d_in[5];
    const float* bv    = (const float*)d_in[6];
    const float* gamma = (const float*)d_in[7];
    float* out = (float*)d_out;

    // ws: qbuf | kbuf | vfw (bf16) | accp (bf16, G slots) | lsump (f32)
    const size_t nQK  = (size_t)BB * PP * 8;        // elems
    const size_t nV   = (size_t)BB * CC * PP;
    const size_t base = 2 * nQK * 2 + nV * 2;       // bytes
    const size_t perG = nV * 2 + (size_t)BB * PP * 4;
    const int G = (ws_size >= base + 4 * perG) ? 4 : 2;
    const int keysPerG = PP / G;
    const int numTiles = keysPerG / 64;

    ushort* qbuf = (ushort*)d_ws;
    ushort* kbuf = qbuf + nQK;
    ushort* vfw  = kbuf + nQK;
    ushort* accp = vfw + nV;
    float* lsump = (float*)(accp + (size_t)G * nV);

    proj4<<<dim3(BB * 2 * QTILES), dim3(256), 0, stream>>>(
        x, Wq, bq, Wk, bk, Wv, bv, qbuf, kbuf, vfw);
    attn11<<<dim3(G * BB * QTILES), dim3(128), 0, stream>>>(
        qbuf, kbuf, vfw, accp, lsump, keysPerG, numTiles);
    combine<<<dim3(576), dim3(256), 0, stream>>>(
        accp, lsump, x, gamma, out, G);
}

// Round 5
// 141.768 us; speedup vs baseline: 1.2899x; 1.2899x over previous
//
#include <hip/hip_runtime.h>
#include <hip/hip_bf16.h>
#include <stdint.h>

// B,C,H,W = 2,64,96,96. Inputs fp32, output fp32.
// proj5: QKV 1x1 convs. x tile (64c x 64px, 16KB) staged to LDS via
//        global_load_lds 16B (coalesced). Wave id via READFIRSTLANE so the
//        10 weight-row pointers are provably wave-uniform -> weight loads
//        are s_loads (round-4's proj4 dropped this: vector loads hoisted
//        -> 640 live VGPRs -> 87MB scratch spill, VGPR=256, 76µs).
//        Inner loop: ds_read_b32 x + v_fmac with SGPR weight operand.
// attn10 (verbatim round-3 winner, 49.7µs): LDS-staged flash attention,
//        double-buffered global_load_lds K+V, V rows XOR-swizzled,
//        Schraudolph bf16 P, VALU lsum + shfl quad-reduce.
// combine: sum G key-split partials, normalize, + gamma*attn + x.
#define BB 2
#define CC 64
#define PP 9216
#define QTILES 144               // PP/64
#define LOG2E 1.4426950408889634f
// big-constant Schraudolph: low16(E*128 + 16248.665 + 1.5*2^23) = bf16 bits of 2^E
#define SCH_BC 12599160.0f

typedef unsigned short ushort;
typedef __attribute__((ext_vector_type(8))) short short8;
typedef __attribute__((ext_vector_type(4))) float floatx4;
typedef __attribute__((ext_vector_type(4))) int intx4;

__device__ __forceinline__ ushort f2bf(float f) {
    unsigned int u = __float_as_uint(f);
    u = (u + 0x7fffu + ((u >> 16) & 1u)) >> 16;   // RNE
    return (ushort)u;
}

// 2^e0, 2^e1 as packed bf16 pair: add-big-constant Schraudolph (no v_cvt),
// then one v_perm_b32 splices the two low16 halves.
__device__ __forceinline__ unsigned int exp2_pk_bf16(float e0, float e1) {
    const float t0 = fmaf(e0, 128.f, SCH_BC);
    const float t1 = fmaf(e1, 128.f, SCH_BC);
    // result bytes: [t0.b0, t0.b1, t1.b0, t1.b1]
    return __builtin_amdgcn_perm(__float_as_uint(t1), __float_as_uint(t0),
                                 0x05040100u);
}

__device__ __forceinline__ void gload16_lds(const void* g, void* lds_base) {
    __builtin_amdgcn_global_load_lds(
        (const __attribute__((address_space(1))) unsigned int*)g,
        (__attribute__((address_space(3))) unsigned int*)lds_base, 16, 0, 0);
}

// ---------------------------------------------------------------------------
// Kernel 1: QKV projection, LDS-staged, scalar weights. 576 blocks x 256
// (4 waves; 2 blocks per 64-px tile, each covering 40 of the 80 output rows;
// wave = 64 px x 10 rows). Rows 0-7: q (*LOG2E), 8-15: k, 16-79: v.
// V keys permuted within 32-groups: slot = ((k>>2)&3)*8 + ((k>>4)&1)*4 + (k&3)
// so PV's B-operand slot k'=quad*8+j matches QK's D[key][q] output rows.
// ---------------------------------------------------------------------------
__global__ __launch_bounds__(256)
void proj5(const float* __restrict__ x,
           const float* __restrict__ Wq, const float* __restrict__ bq,
           const float* __restrict__ Wk, const float* __restrict__ bk,
           const float* __restrict__ Wv, const float* __restrict__ bv,
           ushort* __restrict__ qbuf, ushort* __restrict__ kbuf,
           ushort* __restrict__ vfw)
{
    __shared__ __align__(16) float xs[64 * 64];   // [c][px], 16 KB

    const int tid  = threadIdx.x;
    const int lane = tid & 63;
    // WAVE-UNIFORM wave id: keeps weight-row pointers uniform -> s_loads.
    const int w    = __builtin_amdgcn_readfirstlane(tid >> 6);  // 0..3
    const int blk = blockIdx.x;
    const int b     = blk / (2 * QTILES);
    const int rem   = blk % (2 * QTILES);
    const int ptile = rem >> 1;
    const int rhalf = rem & 1;
    const int p0    = ptile * 64;
    const int p     = p0 + lane;
    const int r0    = rhalf * 40 + w * 10;        // this wave's 10 rows (uniform)

    // ---- stage x tile: 1024 float4 slots; slot s = i*256 + tid ----
    const int w64 = w << 6;                       // wave-uniform base
#pragma unroll
    for (int i = 0; i < 4; ++i) {
        const int s  = i * 256 + tid;
        const int c  = s >> 4;
        const int j4 = (s & 15) << 2;
        gload16_lds(x + ((size_t)(b * 64 + c)) * PP + p0 + j4,
                    (char*)xs + ((size_t)(i * 256 + w64)) * 16);
    }
    __syncthreads();   // vmcnt(0) drain: xs ready

    const float* wrow[10];
#pragma unroll
    for (int r = 0; r < 10; ++r) {
        const int row = r0 + r;                   // uniform
        wrow[r] = (row < 8) ? (Wq + row * 64)
                : (row < 16) ? (Wk + (row - 8) * 64)
                : (Wv + (row - 16) * 64);
    }

    float acc[10];
#pragma unroll
    for (int r = 0; r < 10; ++r) acc[r] = 0.f;
#pragma unroll
    for (int c = 0; c < 64; ++c) {
        const float xc = xs[c * 64 + lane];       // 2 lanes/bank: free
#pragma unroll
        for (int r = 0; r < 10; ++r)
            acc[r] = fmaf(wrow[r][c], xc, acc[r]);   // SGPR weight operand
    }

#pragma unroll
    for (int r = 0; r < 10; ++r) {
        const int row = r0 + r;
        if (row < 8) {
            const float v = (acc[r] + bq[row]) * LOG2E;
            qbuf[((size_t)b * PP + p) * 8 + row] = f2bf(v);
        } else if (row < 16) {
            const float v = acc[r] + bk[row - 8];
            kbuf[((size_t)b * PP + p) * 8 + (row - 8)] = f2bf(v);
        } else {
            const int co = row - 16;
            const float v = acc[r] + bv[co];
            const int pl = p & 31;     // slot permutation within 32-group
            const int ps = (p & ~31) | ((((pl >> 2) & 3) << 3) | (((pl >> 4) & 1) << 2) | (pl & 3));
            vfw[((size_t)b * 64 + co) * PP + ps] = f2bf(v);
        }
    }
}

// ---------------------------------------------------------------------------
// Kernel 2: LDS-staged MFMA flash attention (round-3 attn10, verbatim).
// Grid = G*BB*QTILES blocks of 128 (2 waves = the two 32-key halves of each
// 64-key tile; both share one staged K+V tile: K 1KB + V 8KB per buffer,
// double-buffered, 18.25KB LDS total; epilogue smerge overlays stage bufs).
// Stage: wave0 = K(1 instr) + V ch-rows 0-31 (4 instrs); wave1 = rows 32-63.
// V LDS layout: [ch row 0..63][8 chunks of 16B], chunk_pos = logical ^ (row&7)
// (swizzle applied on global source; ds_read applies the same XOR).
// QK: E = mfma(A=K, B=Q) -> D[key][q]; Q k-slots >=8 zero, K quads broadcast.
// P packed in regs as PV B-operand (V key-permuted). lsum = VALU sum of the
// same bf16 P bits, shfl_xor quad-reduced in the epilogue.
// ---------------------------------------------------------------------------
__global__ __launch_bounds__(128, 3)
void attn10(const ushort* __restrict__ qbuf, const ushort* __restrict__ kbuf,
            const ushort* __restrict__ vfw,
            ushort* __restrict__ accp, float* __restrict__ lsump,
            int keysPerG, int numTiles)
{
    // 0..9216: buf0 (V 8KB + K 1KB) | 9216..18432: buf1 | 18432..18688: slsum
    // smerge (16KB f32) overlays 0..16384 after the loop.
    __shared__ __align__(16) char sbuf[18688];
    float* smerge = (float*)sbuf;
    float* slsum  = (float*)(sbuf + 18432);

    const int tid  = threadIdx.x;
    const int lane = tid & 63;
    const int kh   = tid >> 6;        // wave id = key half (0/1)
    const int col  = lane & 15;
    const int quad = lane >> 4;

    const int qt = blockIdx.x % QTILES;
    const int gb = blockIdx.x / QTILES;
    const int b  = gb % BB;
    const int g  = gb / BB;
    const int q0 = qt * 64;

    const short8 zf = {0, 0, 0, 0, 0, 0, 0, 0};

    // Q fragments (B-operand: B[k=d=quad*8+j][n=q=col]); only quad 0 real.
    short8 qfragB[4];
#pragma unroll
    for (int qh = 0; qh < 4; ++qh)
        qfragB[qh] = (quad == 0)
            ? *(const short8*)(qbuf + ((size_t)b * PP + q0 + qh * 16 + col) * 8)
            : zf;

    floatx4 acc[4][4];
#pragma unroll
    for (int qh = 0; qh < 4; ++qh)
#pragma unroll
        for (int cb = 0; cb < 4; ++cb) acc[qh][cb] = (floatx4){0.f, 0.f, 0.f, 0.f};
    float accL[4] = {0.f, 0.f, 0.f, 0.f};

    const ushort* kB = kbuf + (size_t)b * PP * 8;
    const ushort* vB = vfw + (size_t)b * 64 * PP;
    const int kwbase = g * keysPerG;

    // per-lane staging geometry: lane covers (row-in-8-group vr, chunk_pos lane&7)
    const int vr = lane >> 3;                 // 0..7
    const int vc = (lane & 7) ^ vr;           // swizzled logical chunk for this slot

    auto stage = [&](int t) {
        const int kw = kwbase + t * 64;
        char* Vb = sbuf + (t & 1) * 9216;
        if (kh == 0)
            gload16_lds(kB + (size_t)(kw + lane) * 8, Vb + 8192);  // K: 64 rows x 16B
        const int j0 = kh * 4;
#pragma unroll
        for (int j = 0; j < 4; ++j) {
            const int r = (j0 + j) * 8 + vr;                       // ch row 0..63
            gload16_lds(vB + (size_t)r * PP + kw + vc * 8, Vb + (j0 + j) * 1024);
        }
    };

    auto compute = [&](int t) {
        const char* Vb = sbuf + (t & 1) * 9216;
        const ushort* Kl = (const ushort*)(Vb + 8192);
        // K A-operand rows = keys; all quads read quad0's 16B (broadcast, slots
        // >=8 multiply Q zeros).
        const short8 kf0 = *(const short8*)(Kl + (kh * 32 + col) * 8);
        const short8 kf1 = *(const short8*)(Kl + (kh * 32 + 16 + col) * 8);
        short8 vf[4];
        const int ce = (kh * 4 + quad) ^ (col & 7);   // swizzled chunk to read
#pragma unroll
        for (int cb = 0; cb < 4; ++cb)
            vf[cb] = *(const short8*)(Vb + ((cb * 16 + col) * 8 + ce) * 16);

#pragma unroll
        for (int qh = 0; qh < 4; ++qh) {
            const floatx4 E0 = __builtin_amdgcn_mfma_f32_16x16x32_bf16(
                kf0, qfragB[qh], (floatx4){0.f, 0.f, 0.f, 0.f}, 0, 0, 0);
            const floatx4 E1 = __builtin_amdgcn_mfma_f32_16x16x32_bf16(
                kf1, qfragB[qh], (floatx4){0.f, 0.f, 0.f, 0.f}, 0, 0, 0);

            // Schraudolph bf16 P, packed pairs (slots quad*8 + 0..7)
            intx4 pi;
            pi.x = (int)exp2_pk_bf16(E0[0], E0[1]);
            pi.y = (int)exp2_pk_bf16(E0[2], E0[3]);
            pi.z = (int)exp2_pk_bf16(E1[0], E1[1]);
            pi.w = (int)exp2_pk_bf16(E1[2], E1[3]);
            const short8 pf = __builtin_bit_cast(short8, pi);

            // lsum: sum this lane's 8 P values (f32 from the bf16 bits),
            // balanced tree; quad-reduce deferred to epilogue.
            const unsigned int w0 = (unsigned int)pi.x, w1 = (unsigned int)pi.y;
            const unsigned int w2 = (unsigned int)pi.z, w3 = (unsigned int)pi.w;
            const float s0 = __uint_as_float(w0 << 16) + __uint_as_float(w0 & 0xffff0000u);
            const float s1 = __uint_as_float(w1 << 16) + __uint_as_float(w1 & 0xffff0000u);
            const float s2 = __uint_as_float(w2 << 16) + __uint_as_float(w2 & 0xffff0000u);
            const float s3 = __uint_as_float(w3 << 16) + __uint_as_float(w3 & 0xffff0000u);
            accL[qh] += (s0 + s1) + (s2 + s3);

#pragma unroll
            for (int cb = 0; cb < 4; ++cb)
                acc[qh][cb] = __builtin_amdgcn_mfma_f32_16x16x32_bf16(
                    vf[cb], pf, acc[qh][cb], 0, 0, 0);
        }
    };

    // ---- 2-phase staged main loop ----
    stage(0);
    __syncthreads();                 // drains vmcnt(0): buf0 ready
    for (int t = 0; t < numTiles; ++t) {
        if (t + 1 < numTiles) stage(t + 1);   // into the other buffer
        compute(t);
        __syncthreads();             // stage(t+1) complete + buf[t] reads done
    }

    // lsum quad-reduce: lanes {col, col+16, col+32, col+48} hold the 4 quads
#pragma unroll
    for (int qh = 0; qh < 4; ++qh) {
        accL[qh] += __shfl_xor(accL[qh], 16);
        accL[qh] += __shfl_xor(accL[qh], 32);
    }

    // ---- merge the two waves' key-halves via LDS; wave 0 stores ----
    if (kh == 1) {
#pragma unroll
        for (int qh = 0; qh < 4; ++qh)
#pragma unroll
            for (int cb = 0; cb < 4; ++cb)
#pragma unroll
                for (int r = 0; r < 4; ++r)
                    smerge[(cb * 16 + quad * 4 + r) * 64 + qh * 16 + col] = acc[qh][cb][r];
        if (quad == 0)
#pragma unroll
            for (int qh = 0; qh < 4; ++qh)
                slsum[qh * 16 + col] = accL[qh];
    }
    __syncthreads();
    if (kh == 0) {
        ushort* ab = accp + ((size_t)g * BB + b) * CC * PP;
#pragma unroll
        for (int qh = 0; qh < 4; ++qh)
#pragma unroll
            for (int cb = 0; cb < 4; ++cb)
#pragma unroll
                for (int r = 0; r < 4; ++r) {
                    const int c = cb * 16 + quad * 4 + r;
                    const float v = acc[qh][cb][r] + smerge[c * 64 + qh * 16 + col];
                    ab[(size_t)c * PP + q0 + qh * 16 + col] = f2bf(v);
                }
        if (quad == 0) {
            float* lb = lsump + ((size_t)g * BB + b) * PP + q0;
#pragma unroll
            for (int qh = 0; qh < 4; ++qh)
                lb[qh * 16 + col] = accL[qh] + slsum[qh * 16 + col];
        }
    }
}

// ---------------------------------------------------------------------------
// Kernel 3: combine G partials, normalize, + gamma*attn + x. 576 x 256,
// 8 consecutive pixels per thread (layouts already [b][c][p]-major).
// ---------------------------------------------------------------------------
__global__ __launch_bounds__(256)
void combine(const ushort* __restrict__ accp, const float* __restrict__ lsump,
             const float* __restrict__ x, const float* __restrict__ gamma,
             float* __restrict__ out, int G)
{
    const size_t i8 = ((size_t)blockIdx.x * 256 + threadIdx.x) * 8;
    const int b = (int)(i8 / ((size_t)CC * PP));
    const int p = (int)(i8 % PP);
    const float gm = gamma[0];

    float asum[8] = {}, lst[8] = {};
    for (int g = 0; g < G; ++g) {
        const uint4 av = *(const uint4*)(accp + (size_t)g * (BB * CC * PP) + i8);
        const unsigned int u[4] = {av.x, av.y, av.z, av.w};
#pragma unroll
        for (int k = 0; k < 4; ++k) {
            asum[2 * k]     += __uint_as_float(u[k] << 16);
            asum[2 * k + 1] += __uint_as_float(u[k] & 0xffff0000u);
        }
        const float* lp = lsump + ((size_t)g * BB + b) * PP + p;
        const float4 l0 = *(const float4*)lp;
        const float4 l1 = *(const float4*)(lp + 4);
        lst[0] += l0.x; lst[1] += l0.y; lst[2] += l0.z; lst[3] += l0.w;
        lst[4] += l1.x; lst[5] += l1.y; lst[6] += l1.z; lst[7] += l1.w;
    }

    const float4 x0 = *(const float4*)(x + i8);
    const float4 x1 = *(const float4*)(x + i8 + 4);
    float o[8] = {x0.x, x0.y, x0.z, x0.w, x1.x, x1.y, x1.z, x1.w};
#pragma unroll
    for (int j = 0; j < 8; ++j)
        o[j] = fmaf(asum[j], gm / fmaxf(lst[j], 1e-30f), o[j]);
    *(float4*)(out + i8)     = make_float4(o[0], o[1], o[2], o[3]);
    *(float4*)(out + i8 + 4) = make_float4(o[4], o[5], o[6], o[7]);
}

// ---------------------------------------------------------------------------
extern "C" void kernel_launch(void* const* d_in, const int* in_sizes, int n_in,
                              void* d_out, int out_size, void* d_ws, size_t ws_size,
                              hipStream_t stream)
{
    const float* x     = (const float*)d_in[0];
    const float* Wq    = (const float*)d_in[1];
    const float* bq    = (const float*)d_in[2];
    const float* Wk    = (const float*)d_in[3];
    const float* bk    = (const float*)d_in[4];
    const float* Wv    = (const float*)d_in[5];
    const float* bv    = (const float*)d_in[6];
    const float* gamma = (const float*)d_in[7];
    float* out = (float*)d_out;

    // ws: qbuf | kbuf | vfw (bf16) | accp (bf16, G slots) | lsump (f32)
    const size_t nQK  = (size_t)BB * PP * 8;        // elems
    const size_t nV   = (size_t)BB * CC * PP;
    const size_t base = 2 * nQK * 2 + nV * 2;       // bytes
    const size_t perG = nV * 2 + (size_t)BB * PP * 4;
    const int G = (ws_size >= base + 4 * perG) ? 4 : 2;
    const int keysPerG = PP / G;
    const int numTiles = keysPerG / 64;

    ushort* qbuf = (ushort*)d_ws;
    ushort* kbuf = qbuf + nQK;
    ushort* vfw  = kbuf + nQK;
    ushort* accp = vfw + nV;
    float* lsump = (float*)(accp + (size_t)G * nV);

    proj5<<<dim3(BB * 2 * QTILES), dim3(256), 0, stream>>>(
        x, Wq, bq, Wk, bk, Wv, bv, qbuf, kbuf, vfw);
    attn10<<<dim3(G * BB * QTILES), dim3(128), 0, stream>>>(
        qbuf, kbuf, vfw, accp, lsump, keysPerG, numTiles);
    combine<<<dim3(576), dim3(256), 0, stream>>>(
        accp, lsump, x, gamma, out, G);
}

// Round 6
// 126.155 us; speedup vs baseline: 1.4496x; 1.1238x over previous
//
#include <hip/hip_runtime.h>
#include <hip/hip_bf16.h>
#include <stdint.h>

// B,C,H,W = 2,64,96,96. Inputs fp32, output fp32.
// proj3 (round-0 verbatim): QKV 1x1 convs -> bf16 q(*log2e), k, V key-PERMUTED
//        channel-major. (Round-5 proj5 LDS/scalar-weight variant was +11µs:
//        640 weight scalars >> SGPR file -> s_load chains. Reverted.)
// attn12: LDS-staged flash attention, 3-buffer counted-vmcnt pipeline:
//        raw s_barrier + s_waitcnt vmcnt(5) (never 0 in-loop), stage(t+2)
//        issued at iter t -> ~2 compute-phases for loads to land. Each wave
//        issues exactly 5 global_load_lds per stage (wave1 duplicates K to
//        same bytes). lsum via ones-row MFMA (round-3 put it on the VALU:
//        VALUBusy 38% > MfmaUtil 25% -- wrong pipe). V rows XOR-swizzled.
// combine: sum G key-split partials, normalize, + gamma*attn + x.
#define BB 2
#define CC 64
#define PP 9216
#define QTILES 144               // PP/64
#define LOG2E 1.4426950408889634f
// big-constant Schraudolph: low16(E*128 + 16248.665 + 1.5*2^23) = bf16 bits of 2^E
#define SCH_BC 12599160.0f

typedef unsigned short ushort;
typedef __attribute__((ext_vector_type(8))) short short8;
typedef __attribute__((ext_vector_type(4))) float floatx4;
typedef __attribute__((ext_vector_type(4))) int intx4;

__device__ __forceinline__ ushort f2bf(float f) {
    unsigned int u = __float_as_uint(f);
    u = (u + 0x7fffu + ((u >> 16) & 1u)) >> 16;   // RNE
    return (ushort)u;
}

// 2^e0, 2^e1 as packed bf16 pair: add-big-constant Schraudolph (no v_cvt),
// then one v_perm_b32 splices the two low16 halves.
__device__ __forceinline__ unsigned int exp2_pk_bf16(float e0, float e1) {
    const float t0 = fmaf(e0, 128.f, SCH_BC);
    const float t1 = fmaf(e1, 128.f, SCH_BC);
    // result bytes: [t0.b0, t0.b1, t1.b0, t1.b1]
    return __builtin_amdgcn_perm(__float_as_uint(t1), __float_as_uint(t0),
                                 0x05040100u);
}

__device__ __forceinline__ void gload16_lds(const void* g, void* lds_base) {
    __builtin_amdgcn_global_load_lds(
        (const __attribute__((address_space(1))) unsigned int*)g,
        (__attribute__((address_space(3))) unsigned int*)lds_base, 16, 0, 0);
}

// ---------------------------------------------------------------------------
// Kernel 1: QKV projection (round-0 proj3, verbatim). 576 blocks x 256
// (4 waves; wave = 64 px x 10 rows; 2 blocks per 64-px tile, each covering
// 40 of the 80 output rows). Rows 0-7: q (*LOG2E), 8-15: k, 16-79: v.
// V keys permuted within 32-groups: slot = ((k>>2)&3)*8 + ((k>>4)&1)*4 + (k&3)
// so PV's B-operand slot k'=quad*8+j matches QK's D[key][q] output rows.
// ---------------------------------------------------------------------------
__global__ __launch_bounds__(256)
void proj3(const float* __restrict__ x,
           const float* __restrict__ Wq, const float* __restrict__ bq,
           const float* __restrict__ Wk, const float* __restrict__ bk,
           const float* __restrict__ Wv, const float* __restrict__ bv,
           ushort* __restrict__ qbuf, ushort* __restrict__ kbuf,
           ushort* __restrict__ vfw)
{
    const int tid = threadIdx.x;
    const int px  = tid & 63;
    const int og  = __builtin_amdgcn_readfirstlane(tid >> 6);  // 0..3, wave-uniform
    const int blk = blockIdx.x;
    const int b     = blk / (2 * QTILES);
    const int rem   = blk % (2 * QTILES);
    const int ptile = rem >> 1;
    const int rhalf = rem & 1;
    const int p     = ptile * 64 + px;
    const int r0    = rhalf * 40 + og * 10;      // first of this thread's 10 rows

    const float* wr[10];
#pragma unroll
    for (int r = 0; r < 10; ++r) {
        const int row = r0 + r;
        wr[r] = (row < 8) ? (Wq + row * 64)
              : (row < 16) ? (Wk + (row - 8) * 64)
              : (Wv + (row - 16) * 64);
    }

    float xv[64];
#pragma unroll
    for (int c = 0; c < 64; ++c)
        xv[c] = x[((size_t)b * 64 + c) * PP + p];

    float acc[10];
#pragma unroll
    for (int r = 0; r < 10; ++r) acc[r] = 0.f;
#pragma unroll
    for (int c = 0; c < 64; ++c) {
#pragma unroll
        for (int r = 0; r < 10; ++r)
            acc[r] = fmaf(wr[r][c], xv[c], acc[r]);
    }

#pragma unroll
    for (int r = 0; r < 10; ++r) {
        const int row = r0 + r;
        if (row < 8) {
            const float v = (acc[r] + bq[row]) * LOG2E;
            qbuf[((size_t)b * PP + p) * 8 + row] = f2bf(v);
        } else if (row < 16) {
            const float v = acc[r] + bk[row - 8];
            kbuf[((size_t)b * PP + p) * 8 + (row - 8)] = f2bf(v);
        } else {
            const int co = row - 16;
            const float v = acc[r] + bv[co];
            const int pl = p & 31;     // slot permutation within 32-group
            const int ps = (p & ~31) | ((((pl >> 2) & 3) << 3) | (((pl >> 4) & 1) << 2) | (pl & 3));
            vfw[((size_t)b * 64 + co) * PP + ps] = f2bf(v);
        }
    }
}

// ---------------------------------------------------------------------------
// Kernel 2: LDS-staged MFMA flash attention, 3-buffer counted-vmcnt pipeline.
// Grid = G*BB*QTILES blocks of 128 (2 waves = the two 32-key halves of each
// 64-key tile). Per 9216B buffer: V 8KB (rows XOR-swizzled: slot s = r*8+cs
// holds global chunk cs^(r&7)) + K 1KB. 3 buffers = 27648B; epilogue smerge
// (16KB) overlays bufs 0-1 after the final vmcnt(0)+barrier.
// Loop invariants: each wave issues EXACTLY 5 gload_lds per stage (wave1
// duplicates the K load -> same bytes, benign); at iter-t top outstanding
// <= stage(t)+stage(t+1) = 10 -> vmcnt(5) proves stage(t) landed; barrier
// proves it for both waves AND fences compute(t-1) before stage(t+2)
// overwrites buf[(t+2)%3] (last read at t-1). Final tile peeled, vmcnt(0).
// QK: E = mfma(A=K, B=Q) -> D[key][q]; Q k-slots >=8 zero, K quads broadcast.
// P packed as bf16 bits (Schraudolph) = PV B-operand (V key-permuted).
// lsum = ones-row MFMA over the same P (matrix pipe at 25% has headroom).
// ---------------------------------------------------------------------------
__global__ __launch_bounds__(128, 3)
void attn12(const ushort* __restrict__ qbuf, const ushort* __restrict__ kbuf,
            const ushort* __restrict__ vfw,
            ushort* __restrict__ accp, float* __restrict__ lsump,
            int keysPerG, int numTiles)
{
    // 0..27648: 3x (V 8KB + K 1KB) | 27648..27904: slsum
    // smerge (16KB f32) overlays 0..16384 after the loop.
    __shared__ __align__(16) char sbuf[27904];
    float* smerge = (float*)sbuf;
    float* slsum  = (float*)(sbuf + 27648);

    const int tid  = threadIdx.x;
    const int lane = tid & 63;
    const int kh   = tid >> 6;        // wave id = key half (0/1)
    const int col  = lane & 15;
    const int quad = lane >> 4;

    const int qt = blockIdx.x % QTILES;
    const int gb = blockIdx.x / QTILES;
    const int b  = gb % BB;
    const int g  = gb / BB;
    const int q0 = qt * 64;

    const short8 zf = {0, 0, 0, 0, 0, 0, 0, 0};
    const short vone = (short)0x3F80;                 // bf16 1.0
    const short8 vones = {vone, vone, vone, vone, vone, vone, vone, vone};

    // Q fragments (B-operand: B[k=d=quad*8+j][n=q=col]); only quad 0 real.
    short8 qfragB[4];
#pragma unroll
    for (int qh = 0; qh < 4; ++qh)
        qfragB[qh] = (quad == 0)
            ? *(const short8*)(qbuf + ((size_t)b * PP + q0 + qh * 16 + col) * 8)
            : zf;

    floatx4 acc[4][4];
#pragma unroll
    for (int qh = 0; qh < 4; ++qh)
#pragma unroll
        for (int cb = 0; cb < 4; ++cb) acc[qh][cb] = (floatx4){0.f, 0.f, 0.f, 0.f};
    floatx4 accLh[4];
#pragma unroll
    for (int qh = 0; qh < 4; ++qh) accLh[qh] = (floatx4){0.f, 0.f, 0.f, 0.f};

    const ushort* kB = kbuf + (size_t)b * PP * 8;
    const ushort* vB = vfw + (size_t)b * 64 * PP;
    const int kwbase = g * keysPerG;

    // per-lane staging geometry: lane covers (row-in-8-group vr, chunk_pos lane&7)
    const int vr = lane >> 3;                 // 0..7
    const int vc = (lane & 7) ^ vr;           // swizzled logical chunk for this slot

    auto stage = [&](int t) {
        const int kw = kwbase + t * 64;
        char* Vb = sbuf + 9216 * (t % 3);
        // K: 64 rows x 16B; BOTH waves issue it (same bytes) so each wave's
        // per-stage gload count is exactly 5 (vmcnt accounting).
        gload16_lds(kB + (size_t)(kw + lane) * 8, Vb + 8192);
        const int j0 = kh * 4;
#pragma unroll
        for (int j = 0; j < 4; ++j) {
            const int r = (j0 + j) * 8 + vr;                       // ch row 0..63
            gload16_lds(vB + (size_t)r * PP + kw + vc * 8, Vb + (j0 + j) * 1024);
        }
    };

    auto compute = [&](int t) {
        const char* Vb = sbuf + 9216 * (t % 3);
        const ushort* Kl = (const ushort*)(Vb + 8192);
        // K A-operand rows = keys; all quads read quad0's 16B (broadcast, slots
        // >=8 multiply Q zeros).
        const short8 kf0 = *(const short8*)(Kl + (kh * 32 + col) * 8);
        const short8 kf1 = *(const short8*)(Kl + (kh * 32 + 16 + col) * 8);
        short8 vf[4];
        const int ce = (kh * 4 + quad) ^ (col & 7);   // swizzled chunk to read
#pragma unroll
        for (int cb = 0; cb < 4; ++cb)
            vf[cb] = *(const short8*)(Vb + ((cb * 16 + col) * 8 + ce) * 16);

#pragma unroll
        for (int qh = 0; qh < 4; ++qh) {
            const floatx4 E0 = __builtin_amdgcn_mfma_f32_16x16x32_bf16(
                kf0, qfragB[qh], (floatx4){0.f, 0.f, 0.f, 0.f}, 0, 0, 0);
            const floatx4 E1 = __builtin_amdgcn_mfma_f32_16x16x32_bf16(
                kf1, qfragB[qh], (floatx4){0.f, 0.f, 0.f, 0.f}, 0, 0, 0);

            // Schraudolph bf16 P, packed pairs (slots quad*8 + 0..7)
            intx4 pi;
            pi.x = (int)exp2_pk_bf16(E0[0], E0[1]);
            pi.y = (int)exp2_pk_bf16(E0[2], E0[3]);
            pi.z = (int)exp2_pk_bf16(E1[0], E1[1]);
            pi.w = (int)exp2_pk_bf16(E1[2], E1[3]);
            const short8 pf = __builtin_bit_cast(short8, pi);

            // lsum on the matrix pipe: D[r][c] = sum_k P[k][c] for every r.
            accLh[qh] = __builtin_amdgcn_mfma_f32_16x16x32_bf16(vones, pf, accLh[qh], 0, 0, 0);
#pragma unroll
            for (int cb = 0; cb < 4; ++cb)
                acc[qh][cb] = __builtin_amdgcn_mfma_f32_16x16x32_bf16(
                    vf[cb], pf, acc[qh][cb], 0, 0, 0);
        }
    };

    // ---- 3-buffer counted-vmcnt main loop ----
    stage(0);
    stage(1);                                   // outstanding: 10 per wave
    for (int t = 0; t < numTiles - 1; ++t) {
        asm volatile("s_waitcnt vmcnt(5)" ::: "memory");   // stage(t) landed
        __builtin_amdgcn_s_barrier();                      // both waves agree
        __builtin_amdgcn_sched_barrier(0);
        if (t + 2 < numTiles) stage(t + 2);                // buf[(t+2)%3]
        compute(t);
    }
    asm volatile("s_waitcnt vmcnt(0)" ::: "memory");       // last stage landed
    __builtin_amdgcn_s_barrier();
    __builtin_amdgcn_sched_barrier(0);
    compute(numTiles - 1);
    __syncthreads();            // all buf reads done before smerge overlay

    // ---- merge the two waves' key-halves via LDS; wave 0 stores ----
    if (kh == 1) {
#pragma unroll
        for (int qh = 0; qh < 4; ++qh)
#pragma unroll
            for (int cb = 0; cb < 4; ++cb)
#pragma unroll
                for (int r = 0; r < 4; ++r)
                    smerge[(cb * 16 + quad * 4 + r) * 64 + qh * 16 + col] = acc[qh][cb][r];
        if (quad == 0)
#pragma unroll
            for (int qh = 0; qh < 4; ++qh)
                slsum[qh * 16 + col] = accLh[qh][0];
    }
    __syncthreads();
    if (kh == 0) {
        ushort* ab = accp + ((size_t)g * BB + b) * CC * PP;
#pragma unroll
        for (int qh = 0; qh < 4; ++qh)
#pragma unroll
            for (int cb = 0; cb < 4; ++cb)
#pragma unroll
                for (int r = 0; r < 4; ++r) {
                    const int c = cb * 16 + quad * 4 + r;
                    const float v = acc[qh][cb][r] + smerge[c * 64 + qh * 16 + col];
                    ab[(size_t)c * PP + q0 + qh * 16 + col] = f2bf(v);
                }
        if (quad == 0) {
            float* lb = lsump + ((size_t)g * BB + b) * PP + q0;
#pragma unroll
            for (int qh = 0; qh < 4; ++qh)
                lb[qh * 16 + col] = accLh[qh][0] + slsum[qh * 16 + col];
        }
    }
}

// ---------------------------------------------------------------------------
// Kernel 3: combine G partials, normalize, + gamma*attn + x. 576 x 256,
// 8 consecutive pixels per thread (layouts already [b][c][p]-major).
// ---------------------------------------------------------------------------
__global__ __launch_bounds__(256)
void combine(const ushort* __restrict__ accp, const float* __restrict__ lsump,
             const float* __restrict__ x, const float* __restrict__ gamma,
             float* __restrict__ out, int G)
{
    const size_t i8 = ((size_t)blockIdx.x * 256 + threadIdx.x) * 8;
    const int b = (int)(i8 / ((size_t)CC * PP));
    const int p = (int)(i8 % PP);
    const float gm = gamma[0];

    float asum[8] = {}, lst[8] = {};
    for (int g = 0; g < G; ++g) {
        const uint4 av = *(const uint4*)(accp + (size_t)g * (BB * CC * PP) + i8);
        const unsigned int u[4] = {av.x, av.y, av.z, av.w};
#pragma unroll
        for (int k = 0; k < 4; ++k) {
            asum[2 * k]     += __uint_as_float(u[k] << 16);
            asum[2 * k + 1] += __uint_as_float(u[k] & 0xffff0000u);
        }
        const float* lp = lsump + ((size_t)g * BB + b) * PP + p;
        const float4 l0 = *(const float4*)lp;
        const float4 l1 = *(const float4*)(lp + 4);
        lst[0] += l0.x; lst[1] += l0.y; lst[2] += l0.z; lst[3] += l0.w;
        lst[4] += l1.x; lst[5] += l1.y; lst[6] += l1.z; lst[7] += l1.w;
    }

    const float4 x0 = *(const float4*)(x + i8);
    const float4 x1 = *(const float4*)(x + i8 + 4);
    float o[8] = {x0.x, x0.y, x0.z, x0.w, x1.x, x1.y, x1.z, x1.w};
#pragma unroll
    for (int j = 0; j < 8; ++j)
        o[j] = fmaf(asum[j], gm / fmaxf(lst[j], 1e-30f), o[j]);
    *(float4*)(out + i8)     = make_float4(o[0], o[1], o[2], o[3]);
    *(float4*)(out + i8 + 4) = make_float4(o[4], o[5], o[6], o[7]);
}

// ---------------------------------------------------------------------------
extern "C" void kernel_launch(void* const* d_in, const int* in_sizes, int n_in,
                              void* d_out, int out_size, void* d_ws, size_t ws_size,
                              hipStream_t stream)
{
    const float* x     = (const float*)d_in[0];
    const float* Wq    = (const float*)d_in[1];
    const float* bq    = (const float*)d_in[2];
    const float* Wk    = (const float*)d_in[3];
    const float* bk    = (const float*)d_in[4];
    const float* Wv    = (const float*)d_in[5];
    const float* bv    = (const float*)d_in[6];
    const float* gamma = (const float*)d_in[7];
    float* out = (float*)d_out;

    // ws: qbuf | kbuf | vfw (bf16) | accp (bf16, G slots) | lsump (f32)
    const size_t nQK  = (size_t)BB * PP * 8;        // elems
    const size_t nV   = (size_t)BB * CC * PP;
    const size_t base = 2 * nQK * 2 + nV * 2;       // bytes
    const size_t perG = nV * 2 + (size_t)BB * PP * 4;
    const int G = (ws_size >= base + 4 * perG) ? 4 : 2;
    const int keysPerG = PP / G;
    const int numTiles = keysPerG / 64;             // 36 for G=4

    ushort* qbuf = (ushort*)d_ws;
    ushort* kbuf = qbuf + nQK;
    ushort* vfw  = kbuf + nQK;
    ushort* accp = vfw + nV;
    float* lsump = (float*)(accp + (size_t)G * nV);

    proj3<<<dim3(BB * 2 * QTILES), dim3(256), 0, stream>>>(
        x, Wq, bq, Wk, bk, Wv, bv, qbuf, kbuf, vfw);
    attn12<<<dim3(G * BB * QTILES), dim3(128), 0, stream>>>(
        qbuf, kbuf, vfw, accp, lsump, keysPerG, numTiles);
    combine<<<dim3(576), dim3(256), 0, stream>>>(
        accp, lsump, x, gamma, out, G);
}